// Round 6
// baseline (69.464 us; speedup 1.0000x reference)
//
#include <hip/hip_runtime.h>

// ARIMA(P=16, D=1, Q=16), S0 = 1048577, S = 1048576 diffed samples.
// Output: mean(err^2), one float.  SINGLE dispatch.
//
// R16: RUN 7 -> 8 + skewed LDS address map A(t) = t + 4*(t>>5) on EVERY
// buffer access.  Rationale: k_arima ~26 us vs ~12-17 us pipe model; the
// attackable term is LDS: RUN=7 forced 138 scalar b32 ops/wave (no 16B
// alignment) and the IIR phase had a verified 8-way bank conflict
// (addr = rr+32g -> bank = rr).  With RUN=8 + skew:
//   - any 4-aligned float4 chunk never straddles a 32-float skew boundary
//     and stays 16B-aligned -> u0 reads 25->7 instrs (6x ds_read_b128),
//     stage<0> reads 24->6, stride-1 writes 8->2 (float4);
//   - skew spreads stride-8/1/4 patterns over all 32 banks (2-way = free);
//     stage<1> worst-case 4-way (1.58x, mild); IIR 8-way -> 2-way (free).
// Cost: WTILE 512 => WLOOK 192->256 (redundancy 1.75->2.0, +~50 FMA/thr).
// Per-output FMA chains + summation order bitwise identical -> absmax 0.0.
//
// R15 (kept): fused last-block fan-in: atomicExch publish (m20 coherent) +
// bare s_waitcnt vmcnt(0) + two-level poison-based ticket + RMW-read sum.
// R12 accounting (fits R11-R15): dur = fill(41) + k_arima(~26); kernel
// dispatches in the captured graph are ~free (R15 == R12).
//
// Wave-autonomous: wave w of block b owns outputs [(4b+w)*256, +256);
// 4096 waves = 1024 blocks = exactly 4 blocks/CU.  Private LDS slice
// (2 x 672 floats, skewed): stage series (float4) -> diff+AR u0
// (head-folded) -> 3 even-odd squaring levels (strides 1,2,4; halo 112) ->
// stride-8 order-16 IIR (9-substep warmup = 72 samples, proven margin
// R9/R10) -> wave shfl-reduce -> block combine -> ticket fan-in -> out.

#define S_TOTAL 1048576
#define WCHUNK  256
#define NBLK    1024                 // 4 waves/block -> 4096 waves, no tail
#define WLOOK   256                  // halo 112 + IIR warmup 72 + slack
#define WTILE   512                  // 64 runs of 8 at strides 1,2,4
#define RUN     8
#define SER     532                  // staged series floats (133 float4)
#define GUARD   64                   // zero guard: deepest stage read is -64
#define BUFW    672                  // max skewed index 667; 16B-mult rows
#define POISON  0xAAAAAAAAu          // harness 0xAA fill pattern
#define NSUB    32                   // sub-tickets (NBLK/NSUB = 32 each)
#define SUBSTRIDE 16                 // u32 stride -> one 64B line per slot

__device__ __forceinline__ void wbar() { __builtin_amdgcn_wave_barrier(); }

// skewed LDS float-index: bijective, 16B-alignment-preserving for 4-aligned t
__device__ __forceinline__ int SKEW(int t) { return t + 4 * (t >> 5); }

// per-thread even-odd squaring: cc <- coeffs of A(z)A(-z) in z^2 (cc[0]==1)
__device__ __forceinline__ void square17(float (&cc)[17])
{
    float b[17];
    #pragma unroll
    for (int m = 0; m <= 16; ++m) {
        float s = 0.0f;
        #pragma unroll
        for (int i = 0; i <= 16; ++i) {
            int j = 2 * m - i;        // i+j even -> (-1)^j == (-1)^i
            if (j >= 0 && j <= 16) {
                float t = cc[i] * cc[j];
                s = (i & 1) ? s - t : s + t;
            }
        }
        b[m] = s;
    }
    #pragma unroll
    for (int m = 0; m <= 16; ++m) cc[m] = b[m];
}

// one level: out[k] = sum_j (-1)^j cc[j] * in[k - j*S], k in [0, WTILE)
// exactly 64 runs of 8 -> lane == run, no loop, no bounds check
template <int LOG_S>
__device__ __forceinline__ void stageW(const float* in, float* out,
                                       const float (&cc)[17], int lane)
{
    constexpr int S = 1 << LOG_S;
    wbar();
    const int ob = (lane & (S - 1)) + RUN * S * (lane >> LOG_S);
    float x[16 + RUN];
    if constexpr (LOG_S == 0) {
        // base 48+8L: 4-aligned -> 6x float4 (ds_read_b128), skew-safe
        #pragma unroll
        for (int c = 0; c < 6; ++c) {
            float4 v = *(const float4*)(in + SKEW(GUARD + ob - 16 + 4 * c));
            x[4*c+0] = v.x; x[4*c+1] = v.y; x[4*c+2] = v.z; x[4*c+3] = v.w;
        }
    } else {
        #pragma unroll
        for (int m = 0; m < 16 + RUN; ++m)
            x[m] = in[SKEW(GUARD + ob + S * (m - 16))];
    }
    float o[RUN];
    #pragma unroll
    for (int i = 0; i < RUN; ++i) {
        float acc = x[16 + i];                    // j=0: cc[0] == 1
        #pragma unroll
        for (int j = 1; j <= 16; ++j) {
            float v = x[16 + i - j];
            acc = (j & 1) ? fmaf(-cc[j], v, acc)  // free VOP3 negate
                          : fmaf(cc[j], v, acc);
        }
        o[i] = acc;
    }
    if constexpr (LOG_S == 0) {
        *(float4*)(out + SKEW(GUARD + ob))     = make_float4(o[0],o[1],o[2],o[3]);
        *(float4*)(out + SKEW(GUARD + ob + 4)) = make_float4(o[4],o[5],o[6],o[7]);
    } else {
        #pragma unroll
        for (int i = 0; i < RUN; ++i)
            out[SKEW(GUARD + ob + S * i)] = o[i];
    }
    wbar();
}

__global__ __launch_bounds__(256, 4) void k_arima(const float* __restrict__ series,
                                                  const float* __restrict__ w_ar,
                                                  const float* __restrict__ w_ma,
                                                  float* __restrict__ partials,
                                                  float* __restrict__ out)
{
    __shared__ __align__(16) float buf[8][BUFW];
    __shared__ float redLDS[4];
    __shared__ int lastFlag;

    const int tid  = threadIdx.x;
    const int w    = tid >> 6;        // wave 0..3
    const int lane = tid & 63;

    float* bufA = buf[2 * w];
    float* bufB = buf[2 * w + 1];

    const int wbase = (blockIdx.x * 4 + w) * WCHUNK;   // first output t
    const int T0    = wbase - WLOOK;                   // t of u-tile idx 0
    const int gbase = T0 - 16;                         // series idx of elem 0

    // zero guards, both buffers (guard t in [0,64) -> skewed cells)
    bufA[SKEW(lane)] = 0.0f;
    bufB[SKEW(lane)] = 0.0f;

    // stage series: bufA[SKEW(GUARD+i)] = series[gbase+i], i in [0, SER)
    if (gbase >= 0 && gbase + SER <= S_TOTAL + 1) {    // gbase % 16 == 0
        const float4* gp = (const float4*)(series + gbase);
        #pragma unroll
        for (int c = 0; c < 2; ++c)
            *(float4*)(bufA + SKEW(GUARD + 4 * (c * 64 + lane))) = gp[c * 64 + lane];
        if (lane < SER / 4 - 128)                       // 5 lanes
            *(float4*)(bufA + SKEW(GUARD + 4 * (128 + lane))) = gp[128 + lane];
    } else {   // block 0 wave 0, last wave: clamp (y==0 beyond both ends)
        for (int i = lane; i < SER; i += 64) {
            int g = gbase + i;
            g = min(max(g, 0), S_TOTAL);
            bufA[SKEW(GUARD + i)] = series[g];
        }
    }

    // per-thread coefficient registers (w_ar/w_ma uniform -> s_load)
    float cc[17];
    cc[0] = 1.0f;
    #pragma unroll
    for (int m = 1; m <= 16; ++m) cc[m] = w_ma[16 - m];   // a_m

    wbar();   // staging visible to the wave's own lanes (in-order LDS pipe)

    // u0: diff + AR FIR + head fold (bufA series -> bufB), 64 runs of 8
    {
        const int o0 = RUN * lane;
        float s[17 + RUN], y[16 + RUN];
        #pragma unroll
        for (int c = 0; c < 6; ++c) {       // 6x float4, skew-safe
            float4 v = *(const float4*)(bufA + SKEW(GUARD + o0 + 4 * c));
            s[4*c+0] = v.x; s[4*c+1] = v.y; s[4*c+2] = v.z; s[4*c+3] = v.w;
        }
        s[24] = bufA[SKEW(GUARD + o0 + 24)];
        #pragma unroll
        for (int m = 0; m < 16 + RUN; ++m) y[m] = s[m + 1] - s[m];
        float o[RUN];
        #pragma unroll
        for (int i = 0; i < RUN; ++i) {
            float acc = y[16 + i];                    // j=0 tap == 1
            #pragma unroll
            for (int j = 1; j <= 16; ++j)
                acc = fmaf(-w_ar[16 - j], y[16 + i - j], acc);
            if (T0 < 17) {             // block 0 waves 0/1 only (uniform)
                int t = T0 + o0 + i;
                if (t <= 16) {
                    acc = 0.0f;        // t<=0 -> 0 (e0 added at the end)
                    if (t >= 1) {      // u = y_t + sum_{j<t} a_j y_{t-j}
                        acc = y[16 + i];
                        for (int j = 1; j < t; ++j)
                            acc += w_ma[16 - j] * y[16 + i - j];
                    }
                }
            }
            o[i] = acc;
        }
        *(float4*)(bufB + SKEW(GUARD + o0))     = make_float4(o[0],o[1],o[2],o[3]);
        *(float4*)(bufB + SKEW(GUARD + o0 + 4)) = make_float4(o[4],o[5],o[6],o[7]);
    }

    // 3 squaring levels (wave-fenced, no block barriers)
    stageW<0>(bufB, bufA, cc, lane);  square17(cc);
    stageW<1>(bufA, bufB, cc, lane);  square17(cc);
    stageW<2>(bufB, bufA, cc, lane);  square17(cc);   // cc = c3 now
    // u3 in bufA; valid for tile idx >= 112

    // stride-8 order-16 IIR: lane = residue rr (0..7) x group g (0..7);
    // group g owns tiles [WLOOK+32g, +32) = 4 output substeps; 9 warmup.
    // warmup start tile idx = 184 + rr + 32g >= 112 (halo boundary) ✓
    // max read tile = 184 + 7 + 224 + 96 = 511 ✓ exact fit.
    float acc = 0.0f;
    {
        const int rr   = lane & 7;
        const int g    = lane >> 3;
        const int base = GUARD + WLOOK - 72 + rr + 32 * g;   // 248+rr+32g
        float h[16];
        #pragma unroll
        for (int j = 0; j < 16; ++j) h[j] = 0.0f;
        #pragma unroll
        for (int s = 0; s < 13; ++s) {
            float e = bufA[SKEW(base + 8 * s)];
            #pragma unroll
            for (int j = 0; j < 16; ++j) e = fmaf(-cc[j + 1], h[j], e);
            #pragma unroll
            for (int j = 15; j >= 1; --j) h[j] = h[j - 1];
            h[0] = e;
            if (s >= 9) acc += e * e;
        }
    }

    // wave reduce -> block combine
    #pragma unroll
    for (int off = 32; off > 0; off >>= 1)
        acc += __shfl_down(acc, off, 64);
    if (lane == 0) redLDS[w] = acc;
    __syncthreads();

    if (tid == 0) {
        float tot = redLDS[0] + redLDS[1] + redLDS[2] + redLDS[3];
        int last = 0;
        if (partials) {
            unsigned* tick = (unsigned*)(partials + NBLK);  // sub-ticket base
            // publish: RMW executes at the coherence point (m20, cross-XCD)
            (void)atomicExch(&partials[blockIdx.x], tot);
            // order publish before ticket: wait for the exch ack only
            asm volatile("s_waitcnt vmcnt(0)" ::: "memory");
            unsigned so = atomicAdd(&tick[(blockIdx.x >> 5) * SUBSTRIDE], 1u);
            if (((so - POISON - 31u) & 31u) == 0u) {        // sub-winner (1/32)
                unsigned mo = atomicAdd(&tick[NSUB * SUBSTRIDE], 1u); // master
                last = ((mo - POISON - 31u) & 31u) == 0u;   // global last
            }
        } else {
            // fallback (no ws): old single-atomic path onto the poison
            if (blockIdx.x == 0) {
                float y0 = series[1] - series[0];
                tot += y0 * y0;
            }
            atomicAdd(out, tot * (1.0f / (float)S_TOTAL));
        }
        lastFlag = last;
    }
    __syncthreads();

    if (lastFlag) {                    // block-uniform
        // RMW-reads: coherent by construction, no cache-state assumptions
        float s = 0.0f;
        #pragma unroll
        for (int i = 0; i < NBLK / 256; ++i)
            s += atomicAdd(&partials[tid * (NBLK / 256) + i], 0.0f);
        #pragma unroll
        for (int off = 32; off > 0; off >>= 1)
            s += __shfl_down(s, off, 64);
        if (lane == 0) redLDS[w] = s;
        __syncthreads();
        if (tid == 0) {
            float y0 = series[1] - series[0];      // err_0 = y_0
            float tot = redLDS[0] + redLDS[1] + redLDS[2] + redLDS[3] + y0 * y0;
            out[0] = tot * (1.0f / (float)S_TOTAL);   // clean overwrite
        }
    }
}

extern "C" void kernel_launch(void* const* d_in, const int* in_sizes, int n_in,
                              void* d_out, int out_size, void* d_ws, size_t ws_size,
                              hipStream_t stream) {
    const float* series = (const float*)d_in[0];
    const float* w_ar   = (const float*)d_in[1];
    const float* w_ma   = (const float*)d_in[2];
    float* out = (float*)d_out;

    // layout (floats): [0,1024) partials | [1024, 1536) sub-tickets
    // (32 slots, 16-u32 stride = one 64B line each) | [1536] master (own line)
    float* partials = nullptr;
    if (d_ws && ws_size >= (NBLK + NSUB * SUBSTRIDE + SUBSTRIDE) * sizeof(float))
        partials = (float*)d_ws;

    k_arima<<<NBLK, 256, 0, stream>>>(series, w_ar, w_ma, partials, out);
}

// Round 7
// 68.116 us; speedup vs baseline: 1.0198x; 1.0198x over previous
//
#include <hip/hip_runtime.h>

// ARIMA(P=16, D=1, Q=16), S0 = 1048577, S = 1048576 diffed samples.
// Output: mean(err^2), one float.  Two dispatches: k_prep (1 wave) + k_arima.
//
// R17: remove the grid-uniform redundant VALU.  square17 x3 was 867 FMA per
// thread (54% of all VALU ops), computed IDENTICALLY by all 262144 threads,
// fenced between wbar()s (un-hideable).  k_prep computes c1,c2,c3 once
// (same square17 code -> bitwise-identical coefficients) into d_ws; k_arima
// loads them via uniform-address loads (s_load -> SGPR; FMA with one SGPR
// operand is legal).  Also: IIR h-shift (195 v_movs) replaced by static
// mod-16 rotation h[(s-j)&15] -- all indices compile-time after unroll,
// read/write order bitwise identical.
// Evidence trail: R13 (less work, fewer waves: worse), R15 (fan-in free),
// R16 (LDS vectorize+deconflict: null) -> remaining controllable term is
// per-wave serial VALU; this cuts it ~45%.
//
// R15 (kept): fused last-block fan-in: atomicExch publish (m20 coherent) +
// bare s_waitcnt vmcnt(0) + two-level poison-based ticket + RMW-read sum.
// Geometry = R12/R15 (best measured): WCHUNK=256, NBLK=1024, runs of 7,
// 4 blocks/CU.  Wave-autonomous: wave w of block b owns outputs
// [(4b+w)*256, +256).  Private LDS slice (2 x 536 floats):
//   stage series (float4) -> diff+AR u0 (head-folded) -> 3 even-odd
//   squaring levels (strides 1,2,4; halo 112) -> stride-8 order-16 IIR
//   (9-substep warmup = 72 samples; pole bound lam<=0.89 -> lam^72 <= 2e-4,
//   >=100x margin; R9/R10) -> wave shfl-reduce -> block combine ->
//   ticket fan-in -> out.

#define S_TOTAL 1048576
#define WCHUNK  256
#define NBLK    1024                 // 4 waves/block -> 4096 waves, no tail
#define WLOOK   192                  // halo 112 + IIR warmup 72 + slack 8
#define WTILE   448                  // 64 runs of 7 at strides 1,2,4
#define RUN     7
#define SER     468                  // staged series floats (117 float4)
#define GUARD   64                   // zero guard: deepest stage read is -64
#define BUFW    (GUARD + SER + 4)    // 536 floats (2144 B, 16B-aligned rows)
#define POISON  0xAAAAAAAAu          // harness 0xAA fill pattern
#define NSUB    32                   // sub-tickets (NBLK/NSUB = 32 each)
#define SUBSTRIDE 16                 // u32 stride -> one 64B line per slot
#define COEF_OFF 1600                // float offset of c1,c2,c3 table in ws

__device__ __forceinline__ void wbar() { __builtin_amdgcn_wave_barrier(); }

// per-thread even-odd squaring: cc <- coeffs of A(z)A(-z) in z^2 (cc[0]==1)
__device__ __forceinline__ void square17(float (&cc)[17])
{
    float b[17];
    #pragma unroll
    for (int m = 0; m <= 16; ++m) {
        float s = 0.0f;
        #pragma unroll
        for (int i = 0; i <= 16; ++i) {
            int j = 2 * m - i;        // i+j even -> (-1)^j == (-1)^i
            if (j >= 0 && j <= 16) {
                float t = cc[i] * cc[j];
                s = (i & 1) ? s - t : s + t;
            }
        }
        b[m] = s;
    }
    #pragma unroll
    for (int m = 0; m <= 16; ++m) cc[m] = b[m];
}

// one level: out[k] = sum_j (-1)^j cc[j] * in[k - j*S], k in [0, WTILE)
// exactly 64 runs of 7 -> lane == run, no loop, no bounds check
template <int LOG_S>
__device__ __forceinline__ void stageW(const float* in, float* out,
                                       const float (&cc)[17], int lane)
{
    constexpr int S = 1 << LOG_S;
    wbar();
    const int ob = (lane & (S - 1)) + RUN * S * (lane >> LOG_S);
    float x[16 + RUN];
    #pragma unroll
    for (int m = 0; m < 16 + RUN; ++m)
        x[m] = in[GUARD + ob + S * (m - 16)];
    #pragma unroll
    for (int i = 0; i < RUN; ++i) {
        float acc = x[16 + i];                    // j=0: cc[0] == 1
        #pragma unroll
        for (int j = 1; j <= 16; ++j) {
            float v = x[16 + i - j];
            acc = (j & 1) ? fmaf(-cc[j], v, acc)  // free VOP3 negate
                          : fmaf(cc[j], v, acc);
        }
        out[GUARD + ob + S * i] = acc;
    }
    wbar();
}

// one wave: compute c1, c2, c3 (bitwise-identical to the old in-kernel path)
__global__ __launch_bounds__(64, 1) void k_prep(const float* __restrict__ w_ma,
                                                float* __restrict__ coef)
{
    if (threadIdx.x != 0) return;
    float cc[17];
    cc[0] = 1.0f;
    #pragma unroll
    for (int m = 1; m <= 16; ++m) cc[m] = w_ma[16 - m];
    square17(cc);
    #pragma unroll
    for (int m = 0; m <= 16; ++m) coef[m] = cc[m];        // c1
    square17(cc);
    #pragma unroll
    for (int m = 0; m <= 16; ++m) coef[17 + m] = cc[m];   // c2
    square17(cc);
    #pragma unroll
    for (int m = 0; m <= 16; ++m) coef[34 + m] = cc[m];   // c3
}

__global__ __launch_bounds__(256, 4) void k_arima(const float* __restrict__ series,
                                                  const float* __restrict__ w_ar,
                                                  const float* __restrict__ w_ma,
                                                  float* __restrict__ partials,
                                                  const float* __restrict__ coef,
                                                  float* __restrict__ out)
{
    __shared__ __align__(16) float buf[8][BUFW];
    __shared__ float redLDS[4];
    __shared__ int lastFlag;

    const int tid  = threadIdx.x;
    const int w    = tid >> 6;        // wave 0..3
    const int lane = tid & 63;

    float* bufA = buf[2 * w];
    float* bufB = buf[2 * w + 1];

    const int wbase = (blockIdx.x * 4 + w) * WCHUNK;   // first output t
    const int T0    = wbase - WLOOK;                   // t of u-tile idx 0
    const int gbase = T0 - 16;                         // series idx of elem 0

    // zero guards, both buffers (GUARD == 64 == wave width)
    bufA[lane] = 0.0f;
    bufB[lane] = 0.0f;

    // stage series: bufA[GUARD + i] = series[gbase + i], i in [0, SER)
    if (gbase >= 0 && gbase + SER <= S_TOTAL + 1) {    // gbase % 16 == 0
        const float4* gp = (const float4*)(series + gbase);
        float4* lp = (float4*)(bufA + GUARD);
        lp[lane] = gp[lane];
        if (lane < SER / 4 - 64) lp[64 + lane] = gp[64 + lane];   // 53 lanes
    } else {   // block 0 wave 0, last wave: clamp (y==0 beyond both ends)
        for (int i = lane; i < SER; i += 64) {
            int g = gbase + i;
            g = min(max(g, 0), S_TOTAL);
            bufA[GUARD + i] = series[g];
        }
    }

    // level-0 coefficients (w_ma uniform -> s_load)
    float cc[17];
    cc[0] = 1.0f;
    #pragma unroll
    for (int m = 1; m <= 16; ++m) cc[m] = w_ma[16 - m];   // a_m

    wbar();   // staging visible to the wave's own lanes (in-order LDS pipe)

    // u0: diff + AR FIR + head fold (bufA series -> bufB), 64 runs of 7
    {
        const int o0 = RUN * lane;
        float s[17 + RUN], y[16 + RUN];
        #pragma unroll
        for (int m = 0; m < 17 + RUN; ++m) s[m] = bufA[GUARD + o0 + m];
        #pragma unroll
        for (int m = 0; m < 16 + RUN; ++m) y[m] = s[m + 1] - s[m];
        #pragma unroll
        for (int i = 0; i < RUN; ++i) {
            float acc = y[16 + i];                    // j=0 tap == 1
            #pragma unroll
            for (int j = 1; j <= 16; ++j)
                acc = fmaf(-w_ar[16 - j], y[16 + i - j], acc);
            if (T0 < 17) {             // block 0 wave 0 only (uniform)
                int t = T0 + o0 + i;
                if (t <= 16) {
                    acc = 0.0f;        // t<=0 -> 0 (e0 added at the end)
                    if (t >= 1) {      // u = y_t + sum_{j<t} a_j y_{t-j}
                        acc = y[16 + i];
                        for (int j = 1; j < t; ++j)
                            acc += w_ma[16 - j] * y[16 + i - j];
                    }
                }
            }
            bufB[GUARD + o0 + i] = acc;
        }
    }

    // 3 squaring levels; coefficient levels come from k_prep's table
    // (uniform s_loads) instead of 289 redundant FMAs per thread per level.
    stageW<0>(bufB, bufA, cc, lane);
    if (coef) {
        #pragma unroll
        for (int m = 0; m <= 16; ++m) cc[m] = coef[m];        // c1
    } else square17(cc);
    stageW<1>(bufA, bufB, cc, lane);
    if (coef) {
        #pragma unroll
        for (int m = 0; m <= 16; ++m) cc[m] = coef[17 + m];   // c2
    } else square17(cc);
    stageW<2>(bufB, bufA, cc, lane);
    if (coef) {
        #pragma unroll
        for (int m = 0; m <= 16; ++m) cc[m] = coef[34 + m];   // c3
    } else square17(cc);
    // u3 in bufA; valid for tile idx >= 112

    // stride-8 order-16 IIR: lane = residue rr (0..7) x group g (0..7);
    // group g owns rows 4g..4g+3; 9 warmup + 4 output substeps.
    // warmup start tile idx = 120 + rr + 32g >= 112 (halo boundary) ✓
    // h rotation: h[i] holds e_i (substep i); unwritten slots (i>s) are the
    // zero-init -> static mod-16 indices after unroll, no shift movs.
    float acc = 0.0f;
    {
        const int rr   = lane & 7;
        const int g    = lane >> 3;
        const int base = GUARD + WLOOK - 72 + rr + 32 * g;
        float h[16];
        #pragma unroll
        for (int j = 0; j < 16; ++j) h[j] = 0.0f;
        #pragma unroll
        for (int s = 0; s < 13; ++s) {
            float e = bufA[base + 8 * s];
            #pragma unroll
            for (int j = 1; j <= 16; ++j)
                e = fmaf(-cc[j], h[(s - j) & 15], e);   // e_{s-j}; wrapped=0
            h[s & 15] = e;
            if (s >= 9) acc += e * e;
        }
    }

    // wave reduce -> block combine
    #pragma unroll
    for (int off = 32; off > 0; off >>= 1)
        acc += __shfl_down(acc, off, 64);
    if (lane == 0) redLDS[w] = acc;
    __syncthreads();

    if (tid == 0) {
        float tot = redLDS[0] + redLDS[1] + redLDS[2] + redLDS[3];
        int last = 0;
        if (partials) {
            unsigned* tick = (unsigned*)(partials + NBLK);  // sub-ticket base
            // publish: RMW executes at the coherence point (m20, cross-XCD)
            (void)atomicExch(&partials[blockIdx.x], tot);
            // order publish before ticket: wait for the exch ack only
            asm volatile("s_waitcnt vmcnt(0)" ::: "memory");
            unsigned so = atomicAdd(&tick[(blockIdx.x >> 5) * SUBSTRIDE], 1u);
            if (((so - POISON - 31u) & 31u) == 0u) {        // sub-winner (1/32)
                unsigned mo = atomicAdd(&tick[NSUB * SUBSTRIDE], 1u); // master
                last = ((mo - POISON - 31u) & 31u) == 0u;   // global last
            }
        } else {
            // fallback (no ws): old single-atomic path onto the poison
            if (blockIdx.x == 0) {
                float y0 = series[1] - series[0];
                tot += y0 * y0;
            }
            atomicAdd(out, tot * (1.0f / (float)S_TOTAL));
        }
        lastFlag = last;
    }
    __syncthreads();

    if (lastFlag) {                    // block-uniform
        // RMW-reads: coherent by construction, no cache-state assumptions
        float s = 0.0f;
        #pragma unroll
        for (int i = 0; i < NBLK / 256; ++i)
            s += atomicAdd(&partials[tid * (NBLK / 256) + i], 0.0f);
        #pragma unroll
        for (int off = 32; off > 0; off >>= 1)
            s += __shfl_down(s, off, 64);
        if (lane == 0) redLDS[w] = s;
        __syncthreads();
        if (tid == 0) {
            float y0 = series[1] - series[0];      // err_0 = y_0
            float tot = redLDS[0] + redLDS[1] + redLDS[2] + redLDS[3] + y0 * y0;
            out[0] = tot * (1.0f / (float)S_TOTAL);   // clean overwrite
        }
    }
}

extern "C" void kernel_launch(void* const* d_in, const int* in_sizes, int n_in,
                              void* d_out, int out_size, void* d_ws, size_t ws_size,
                              hipStream_t stream) {
    const float* series = (const float*)d_in[0];
    const float* w_ar   = (const float*)d_in[1];
    const float* w_ma   = (const float*)d_in[2];
    float* out = (float*)d_out;

    // ws layout (floats): [0,1024) partials | [1024,1536) sub-tickets
    // (32 slots, 16-u32 stride) | [1536] master line | [1600,1651) coef table
    float* partials = nullptr;
    float* coef     = nullptr;
    if (d_ws && ws_size >= (COEF_OFF + 51) * sizeof(float)) {
        partials = (float*)d_ws;
        coef     = (float*)d_ws + COEF_OFF;
    }

    if (coef) k_prep<<<1, 64, 0, stream>>>(w_ma, coef);
    k_arima<<<NBLK, 256, 0, stream>>>(series, w_ar, w_ma, partials, coef, out);
}